// Round 13
// baseline (222.129 us; speedup 1.0000x reference)
//
#include <hip/hip_runtime.h>
#include <stdint.h>

// ---------------- problem constants ----------------
#define S_LEN 256
#define OUT1  262      // S + 7 - 1
#define K1SEL 131      // ceil((2-1)/2 * 262)
#define OUT2  135      // 131 + 5 - 1
// ws layout (floats)
#define W1T_OFF 0          // w1t[d][k][f]      64*7*8   = 3584
#define W2T_OFF 3584       // w2t[g][ic][k][f2] 32*8*5*16= 20480
#define B1C_OFF 24064      // b1c[r2][f]        32*8
#define B2C_OFF 24320      // b2c[r3][f2]       16*16
#define WREG    1120       // floats per wave LDS region

typedef float v2f __attribute__((ext_vector_type(2)));
__device__ __forceinline__ v2f fma2(v2f a, v2f b, v2f c) {
    return __builtin_elementwise_fma(a, b, c);   // -> v_pk_fma_f32 (exact fma/lane)
}

__device__ __forceinline__ int lane_prefix(unsigned long long m) {
    return __builtin_amdgcn_mbcnt_hi((uint32_t)(m >> 32),
           __builtin_amdgcn_mbcnt_lo((uint32_t)m, 0));
}
__device__ __forceinline__ uint32_t f2ord(float x) {
    uint32_t b = __float_as_uint(x);
    return (b & 0x80000000u) ? ~b : (b | 0x80000000u);
}
__device__ __forceinline__ float ord2f(uint32_t s) {
    uint32_t b = (s & 0x80000000u) ? (s & 0x7FFFFFFFu) : ~s;
    return __uint_as_float(b);
}
// tanh via hw rcp: (e-1)*rcp(e+1), e=exp(2x). applied strictly AFTER selection.
__device__ __forceinline__ float fast_tanh(float x) {
    float e = __expf(2.0f * x);
    return (e - 1.0f) * __builtin_amdgcn_rcpf(e + 1.0f);
}
typedef unsigned long long u64;
__device__ __forceinline__ u64 shflx64(u64 v, int m) {
    uint32_t lo = (uint32_t)__shfl_xor((int)(uint32_t)v, m, 64);
    uint32_t hi = (uint32_t)__shfl_xor((int)(uint32_t)(v >> 32), m, 64);
    return ((u64)hi << 32) | lo;
}
__device__ __forceinline__ u64 maxu64(u64 a, u64 b) { return a > b ? a : b; }
__device__ __forceinline__ u64 minu64(u64 a, u64 b) { return a < b ? a : b; }

// ------------- prep: transpose weights / fold biases into ws; init out with bias -------------
extern "C" __global__ void dcnn_prep(const float* __restrict__ w1, const float* __restrict__ b1,
                                     const float* __restrict__ w2, const float* __restrict__ b2,
                                     const float* __restrict__ fcb, float* __restrict__ out,
                                     float* __restrict__ ws) {
    int i = blockIdx.x * 256 + threadIdx.x;   // 96*256 == 24576
    if (i < 3072) out[i] = fcb[i % 6];        // out[s*6+n] = fcb[n]
    if (i < W2T_OFF) {                        // w1t[d][k][f] = w1[(d*8+f)*7 + k]
        int d = i / 56, r = i % 56, k = r / 8, f = r % 8;
        ws[i] = w1[(d * 8 + f) * 7 + k];
    } else if (i < B1C_OFF) {                 // w2t[g][ic][k][f2] = w2[((g*16+f2)*8+ic)*5+k]
        int q = i - W2T_OFF;
        int g = q / 640, r = q % 640;
        int ic = r / 80, r2 = r % 80;
        int k = r2 / 16, f2 = r2 % 16;
        ws[i] = w2[((g * 16 + f2) * 8 + ic) * 5 + k];
    } else if (i < B2C_OFF) {                 // b1c[r2][f] = b1[2r2*8+f] + b1[(2r2+1)*8+f]
        int q = i - B1C_OFF;
        int r2 = q / 8, f = q % 8;
        ws[i] = b1[(2 * r2) * 8 + f] + b1[(2 * r2 + 1) * 8 + f];
    } else {                                  // b2c[r3][f2]
        int q = i - B2C_OFF;
        int r3 = q / 16, f2 = q % 16;
        ws[i] = b2[(2 * r3) * 16 + f2] + b2[(2 * r3 + 1) * 16 + f2];
    }
}

// ------------- main: one block = one fold pair (128 thr, 2 waves); grid 8192 -------------
// R13: block = minimal coupling unit (slice sl x 2 rs-halves). LDS/block ~10.3 KB
// -> ~15 blocks/CU residency (vs ~4 at R12's 19.5 KB), and every barrier couples
// only 2 waves (minimal imbalance). Math identical to R12; FC partials now
// 64-feature per block (atomic re-association only).
// Per-wave LDS region (WREG=1120 floats): phase A rows float2[272] (guards),
// phase B p1[8][140] (data at +4, zero guards); pair region (2240): a2 sum +
// top4 scratch [f2:16][137].
// R12: rcp-tanh + dense post-pass. R11: v_pk_fma_f32 convs. R9: waves_per_eu(4,8)
// ((6,8) over-squeezed to 40 VGPR + spill). R8: select stays 2-way interleaved.
// R3: all acc/u indices compile-time (runtime index => array to scratch).
extern "C" __global__
__attribute__((amdgpu_flat_work_group_size(128, 128), amdgpu_waves_per_eu(4, 8)))
void dcnn_main(const int* __restrict__ x, const float* __restrict__ emb,
               const float* __restrict__ fcw, const float* __restrict__ ws,
               float* __restrict__ out) {
    __shared__ float uni[2 * WREG];       // 8960 B (pair region)
    __shared__ int   xs[S_LEN];           // 1 KB
    __shared__ float p2loc[64];           // this block's 64 FC features (raw, pre-tanh)
    __shared__ float fred6[6];

    const int tid    = threadIdx.x;
    const int lane   = tid & 63;
    const int wv     = __builtin_amdgcn_readfirstlane(tid >> 6);  // 0..1
    const int sample = blockIdx.x >> 4;
    const int sl     = blockIdx.x & 15;      // global slice r3 in [0,16)
    const int rs     = wv;                   // which half of the fold pair

    const float* w1t = ws + W1T_OFF;
    const float* w2t = ws + W2T_OFF;
    const float* b1c = ws + B1C_OFF;
    const float* b2c = ws + B2C_OFF;

    xs[tid]       = x[sample * S_LEN + tid];
    xs[tid + 128] = x[sample * S_LEN + tid + 128];
    __syncthreads();

    float*  reg   = uni + wv * WREG;
    float2* rowsW = (float2*)reg;          // 272 float2 = 544 floats
    float*  p1w   = reg;                   // [f:8][140]

    // ---- guards + stage 2 embedding rows (d = 4sl+2rs, +1) as float2 per j ----
    if (lane < 8) {
        rowsW[lane]       = make_float2(0.f, 0.f);
        rowsW[264 + lane] = make_float2(0.f, 0.f);
    }
    const int dbase = 4 * sl + 2 * rs;
#pragma unroll
    for (int m = 0; m < 4; ++m) {
        int j  = lane + 64 * m;            // input pos 0..255
        int xi = xs[j];
        rowsW[8 + j] = *(const float2*)(emb + (size_t)xi * 64 + dbase);
    }

    // ---- conv1 (K=7, depthwise) + fold: 8 channels as 4 packed pairs ----
    v2f acc2[4][5];
#pragma unroll
    for (int j = 0; j < 4; ++j) {
        v2f bz = *(const v2f*)(b1c + (2 * sl + rs) * 8 + 2 * j);
#pragma unroll
        for (int m = 0; m < 5; ++m) acc2[j][m] = bz;
    }
    int tA[5];
#pragma unroll
    for (int m = 0; m < 5; ++m) { int t = lane + 64 * m; tA[m] = (t < OUT1) ? t : (OUT1 - 1); }

#pragma unroll 1
    for (int k = 0; k < 7; ++k) {
        v2f wa[4], wb[4];
#pragma unroll
        for (int j = 0; j < 4; ++j) {
            wa[j] = *(const v2f*)(w1t + (dbase * 7 + k) * 8 + 2 * j);
            wb[j] = *(const v2f*)(w1t + ((dbase + 1) * 7 + k) * 8 + 2 * j);
        }
#pragma unroll
        for (int m = 0; m < 5; ++m) {
            float2 v = rowsW[tA[m] + 2 + k];   // j = t-6+k, +8 guard offset
            v2f vx = { v.x, v.x };
            v2f vy = { v.y, v.y };
#pragma unroll
            for (int j = 0; j < 4; ++j) {
                acc2[j][m] = fma2(wa[j], vx, acc2[j][m]);
                acc2[j][m] = fma2(wb[j], vy, acc2[j][m]);
            }
        }
    }

    // ---- p1 guards (rows region dead; p1 aliases it). 64 lanes = 8 ch x 8 slots ----
    {
        int c = lane >> 3, j = lane & 7;
        int pos = (j < 4) ? j : (131 + j);
        p1w[c * 140 + pos] = 0.f;
    }

    // ---- exact order-preserving top-131 per channel, 2 channels interleaved ----
    // channel pair (2cp, 2cp+1) = (.x, .y) of acc2[cp]. 16-bit early-exit radix;
    // keep-set provably identical to full 32-bit select. Writes RAW values.
    // Sentinel cndmask only at m=4 (m<4 has t<256<OUT1 always).
#pragma unroll
    for (int cp = 0; cp < 4; ++cp) {
        uint32_t uA[5], uB[5];
#pragma unroll
        for (int m = 0; m < 4; ++m) {
            uA[m] = f2ord(acc2[cp][m].x);
            uB[m] = f2ord(acc2[cp][m].y);
        }
        uA[4] = (lane < 6) ? f2ord(acc2[cp][4].x) : 0u;   // t=lane+256 < 262
        uB[4] = (lane < 6) ? f2ord(acc2[cp][4].y) : 0u;
        uint32_t preA = 0, preB = 0;
#pragma unroll 1
        for (int bit = 31; bit >= 16; --bit) {
            uint32_t cA = preA | (1u << bit);
            uint32_t cB = preB | (1u << bit);
            int na = 0, nb = 0;
#pragma unroll
            for (int m = 0; m < 5; ++m) {
                na += __popcll(__ballot(uA[m] >= cA));
                nb += __popcll(__ballot(uB[m] >= cB));
            }
            if (na >= K1SEL) preA = cA;
            if (nb >= K1SEL) preB = cB;
        }
        // class-level counts: g = #(>prefix class), e = #(== prefix class)
        int gA = 0, gB = 0, eA = 0, eB = 0;
        uint32_t pA16 = preA >> 16, pB16 = preB >> 16;
#pragma unroll
        for (int m = 0; m < 5; ++m) {
            gA += __popcll(__ballot((uA[m] >> 16) >  pA16));
            eA += __popcll(__ballot((uA[m] >> 16) == pA16));
            gB += __popcll(__ballot((uB[m] >> 16) >  pB16));
            eB += __popcll(__ballot((uB[m] >> 16) == pB16));
        }
        uint32_t msk = 0xFFFF0000u;
        int cgtA, cgtB;
        if ((K1SEL - gA < eA) || (K1SEL - gB < eB)) {
            // boundary collision in top-16 bits: refine low 16 bits (both channels)
#pragma unroll 1
            for (int bit = 15; bit >= 0; --bit) {
                uint32_t cA = preA | (1u << bit);
                uint32_t cB = preB | (1u << bit);
                int na = 0, nb = 0;
#pragma unroll
                for (int m = 0; m < 5; ++m) {
                    na += __popcll(__ballot(uA[m] >= cA));
                    nb += __popcll(__ballot(uB[m] >= cB));
                }
                if (na >= K1SEL) preA = cA;
                if (nb >= K1SEL) preB = cB;
            }
            msk = 0xFFFFFFFFu;
            cgtA = 0; cgtB = 0;
#pragma unroll
            for (int m = 0; m < 5; ++m) {
                cgtA += __popcll(__ballot(uA[m] > preA));
                cgtB += __popcll(__ballot(uB[m] > preB));
            }
        } else {        // count-reuse: class-level strict-greater IS cgt (low pre bits 0)
            cgtA = gA; cgtB = gB;
        }
        const int needA = K1SEL - cgtA;            // #ties kept (earliest t first)
        const int needB = K1SEL - cgtB;
        float* dstA = p1w + (2 * cp) * 140 + 4;
        float* dstB = p1w + (2 * cp + 1) * 140 + 4;
        int eqA = 0, kpA = 0, eqB = 0, kpB = 0;
#pragma unroll
        for (int m = 0; m < 5; ++m) {
            uint32_t umA = uA[m] & msk;
            uint32_t umB = uB[m] & msk;
            unsigned long long emA = __ballot(umA == preA);
            unsigned long long emB = __ballot(umB == preB);
            int erA = eqA + lane_prefix(emA);
            int erB = eqB + lane_prefix(emB);
            bool keepA = (umA > preA) || ((umA == preA) && (erA < needA));
            bool keepB = (umB > preB) || ((umB == preB) && (erB < needB));
            unsigned long long kmA = __ballot(keepA);
            unsigned long long kmB = __ballot(keepB);
            int posA = kpA + lane_prefix(kmA);     // order-preserving compaction
            int posB = kpB + lane_prefix(kmB);
            if (keepA) dstA[posA] = ord2f(uA[m]);  // RAW value (exact bijection)
            if (keepB) dstB[posB] = ord2f(uB[m]);
            eqA += __popcll(emA); kpA += __popcll(kmA);
            eqB += __popcll(emB); kpB += __popcll(kmB);
        }
    }

    // ---- dense tanh post-pass over the whole p1 region (1120 floats) ----
#pragma unroll
    for (int i = 0; i < 17; ++i) {
        int idx = lane + 64 * i;
        p1w[idx] = fast_tanh(p1w[idx]);
    }
    if (lane < 32) {
        int idx = lane + 64 * 17;
        p1w[idx] = fast_tanh(p1w[idx]);
    }

    // ---- conv2 partial: group g = 2sl+rs; 16 f2 as 8 packed pairs ----
    v2f a2v[8][3];
    {
        const v2f* b2v = (const v2f*)(b2c + sl * 16);
#pragma unroll
        for (int j = 0; j < 8; ++j) {
            v2f bz = rs ? (v2f){0.f, 0.f} : b2v[j];   // pre-folded bias counted once
            a2v[j][0] = bz; a2v[j][1] = bz; a2v[j][2] = bz;
        }
    }
    int tB[3];
#pragma unroll
    for (int tm = 0; tm < 3; ++tm) { int t = lane + 64 * tm; tB[tm] = (t < OUT2) ? t : (OUT2 - 1); }

    const int g = 2 * sl + rs;
#pragma unroll 1
    for (int ic = 0; ic < 8; ++ic) {
        const float* src = p1w + ic * 140;   // logical t' = idx - 4
        float win[3][5];                     // straight-line window loads (ds_read2-able)
#pragma unroll
        for (int m = 0; m < 3; ++m) {
            win[m][0] = src[tB[m]];     win[m][1] = src[tB[m] + 1];
            win[m][2] = src[tB[m] + 2]; win[m][3] = src[tB[m] + 3];
            win[m][4] = src[tB[m] + 4];
        }
#pragma unroll
        for (int k = 0; k < 5; ++k) {
            const v2f* wv2 = (const v2f*)(w2t + ((g * 8 + ic) * 5 + k) * 16);
            v2f s0 = { win[0][k], win[0][k] };
            v2f s1 = { win[1][k], win[1][k] };
            v2f s2 = { win[2][k], win[2][k] };
#pragma unroll
            for (int j = 0; j < 8; ++j) {
                v2f w = wv2[j];
                a2v[j][0] = fma2(w, s0, a2v[j][0]);
                a2v[j][1] = fma2(w, s1, a2v[j][1]);
                a2v[j][2] = fma2(w, s2, a2v[j][2]);
            }
        }
    }

    // ---- cross-wave fold (a2 sum) in the pair's dead p1 regions ----
    float* scr = uni;                         // 2240 floats >= 16*137
    __syncthreads();                          // both halves' conv2 done
    if (rs) {
#pragma unroll
        for (int j = 0; j < 8; ++j) {
            scr[(2 * j) * 137 + lane]           = a2v[j][0].x;
            scr[(2 * j + 1) * 137 + lane]       = a2v[j][0].y;
            scr[(2 * j) * 137 + lane + 64]      = a2v[j][1].x;
            scr[(2 * j + 1) * 137 + lane + 64]  = a2v[j][1].y;
            if (lane + 128 < OUT2) {
                scr[(2 * j) * 137 + lane + 128]     = a2v[j][2].x;
                scr[(2 * j + 1) * 137 + lane + 128] = a2v[j][2].y;
            }
        }
    }
    __syncthreads();
    if (!rs) {
#pragma unroll
        for (int j = 0; j < 8; ++j) {
            scr[(2 * j) * 137 + lane]           += a2v[j][0].x;
            scr[(2 * j + 1) * 137 + lane]       += a2v[j][0].y;
            scr[(2 * j) * 137 + lane + 64]      += a2v[j][1].x;
            scr[(2 * j + 1) * 137 + lane + 64]  += a2v[j][1].y;
            if (lane + 128 < OUT2) {
                scr[(2 * j) * 137 + lane + 128]     += a2v[j][2].x;
                scr[(2 * j + 1) * 137 + lane + 128] += a2v[j][2].y;
            }
        }
    }
    __syncthreads();                          // sums visible to both waves

    // ---- top-4 (value desc, tie -> lower t): BOTH waves, 8 lanes per f2 ----
    {
        const int f2o = (lane >> 3) + 8 * rs;  // this wave's 8 f2 channels
        const int seg = lane & 7;              // segment of 17 (last has 16)
        const int tstart = seg * 17;
        const int tend = (seg == 7) ? (OUT2 - 119) : 17;
        const float* src = scr + f2o * 137 + tstart;
        const uint32_t tb = 0xFFFFFFFFu - (uint32_t)tstart;
        u64 L0 = 0, L1 = 0, L2 = 0, L3 = 0;    // sentinels (lose to any finite)
#pragma unroll 1
        for (int i = 0; i < 17; ++i) {
            float v = src[(i < tend) ? i : 0];
            u64 kk = ((u64)f2ord(v) << 32) | (u64)(tb - (uint32_t)i);
            if (i >= tend) kk = 0;
            bool b0 = kk > L0, b1 = kk > L1, b2 = kk > L2, b3 = kk > L3;
            L3 = b3 ? (b2 ? L2 : kk) : L3;
            L2 = b2 ? (b1 ? L1 : kk) : L2;
            L1 = b1 ? (b0 ? L0 : kk) : L1;
            L0 = b0 ? kk : L0;
        }
        // merge 8 segments: 3 shfl rounds; r_i = min_{j+l=i} max(A_j,B_l)
#pragma unroll
        for (int d = 1; d <= 4; d <<= 1) {
            u64 M0 = shflx64(L0, d), M1 = shflx64(L1, d);
            u64 M2 = shflx64(L2, d), M3 = shflx64(L3, d);
            u64 r0 = maxu64(L0, M0);
            u64 r1 = minu64(maxu64(L0, M1), maxu64(L1, M0));
            u64 r2 = minu64(minu64(maxu64(L0, M2), maxu64(L1, M1)), maxu64(L2, M0));
            u64 r3k = minu64(minu64(maxu64(L0, M3), maxu64(L1, M2)),
                             minu64(maxu64(L2, M1), maxu64(L3, M0)));
            L0 = r0; L1 = r1; L2 = r2; L3 = r3k;
        }
        if (seg == 0) {
            // reorder by t ascending == low-32 word descending; emit raw (tanh in FC)
#define CSW2(a, bb) { if ((uint32_t)(bb) > (uint32_t)(a)) { u64 tt = (a); (a) = (bb); (bb) = tt; } }
            CSW2(L0, L1); CSW2(L2, L3); CSW2(L0, L2); CSW2(L1, L3); CSW2(L1, L2);
#undef CSW2
            float* qp = &p2loc[f2o * 4];
            qp[0] = ord2f((uint32_t)(L0 >> 32));
            qp[1] = ord2f((uint32_t)(L1 >> 32));
            qp[2] = ord2f((uint32_t)(L2 >> 32));
            qp[3] = ord2f((uint32_t)(L3 >> 32));
        }
    }
    __syncthreads();

    // ---- FC partial over this block's 64 features (wave 0) + atomic out ----
    if (wv == 0) {
        float pv = fast_tanh(p2loc[lane]);
        float part[6];
#pragma unroll
        for (int n = 0; n < 6; ++n) part[n] = pv * fcw[n * 1024 + sl * 64 + lane];
#pragma unroll
        for (int n = 0; n < 6; ++n) {
            float s = part[n];
#pragma unroll
            for (int off = 32; off > 0; off >>= 1) s += __shfl_xor(s, off, 64);
            if (lane == 0) fred6[n] = s;
        }
        if (lane < 6) atomicAdd(&out[sample * 6 + lane], fred6[lane]);
    }
}

extern "C" void kernel_launch(void* const* d_in, const int* in_sizes, int n_in,
                              void* d_out, int out_size, void* d_ws, size_t ws_size,
                              hipStream_t stream) {
    (void)in_sizes; (void)n_in; (void)out_size; (void)ws_size;
    const int*   x   = (const int*)d_in[0];
    const float* emb = (const float*)d_in[1];
    const float* w1  = (const float*)d_in[2];
    const float* b1  = (const float*)d_in[3];
    const float* w2  = (const float*)d_in[4];
    const float* b2  = (const float*)d_in[5];
    const float* fcw = (const float*)d_in[6];
    const float* fcb = (const float*)d_in[7];
    float* outp = (float*)d_out;
    float* wsf  = (float*)d_ws;   // weights+biases: 24576 floats

    dcnn_prep<<<96, 256, 0, stream>>>(w1, b1, w2, b2, fcb, outp, wsf);
    dcnn_main<<<8192, 128, 0, stream>>>(x, emb, fcw, wsf, outp);
}

// Round 14
// 211.981 us; speedup vs baseline: 1.0479x; 1.0479x over previous
//
#include <hip/hip_runtime.h>
#include <stdint.h>

// ---------------- problem constants ----------------
#define S_LEN 256
#define OUT1  262      // S + 7 - 1
#define K1SEL 131      // ceil((2-1)/2 * 262)
#define OUT2  135      // 131 + 5 - 1
// ws layout (floats)
#define W1T_OFF 0          // w1t[d][k][f]      64*7*8   = 3584
#define W2T_OFF 3584       // w2t[g][ic][k][f2] 32*8*5*16= 20480
#define B1C_OFF 24064      // b1c[r2][f]        32*8
#define B2C_OFF 24320      // b2c[r3][f2]       16*16
#define WREG    1120       // floats per wave LDS region

typedef float v2f __attribute__((ext_vector_type(2)));
__device__ __forceinline__ v2f fma2(v2f a, v2f b, v2f c) {
    return __builtin_elementwise_fma(a, b, c);   // -> v_pk_fma_f32 (exact fma/lane)
}

__device__ __forceinline__ int lane_prefix(unsigned long long m) {
    return __builtin_amdgcn_mbcnt_hi((uint32_t)(m >> 32),
           __builtin_amdgcn_mbcnt_lo((uint32_t)m, 0));
}
__device__ __forceinline__ uint32_t f2ord(float x) {
    uint32_t b = __float_as_uint(x);
    return (b & 0x80000000u) ? ~b : (b | 0x80000000u);
}
__device__ __forceinline__ float ord2f(uint32_t s) {
    uint32_t b = (s & 0x80000000u) ? (s & 0x7FFFFFFFu) : ~s;
    return __uint_as_float(b);
}
// tanh via hw rcp: (e-1)*rcp(e+1), e=exp(2x). applied strictly AFTER selection.
__device__ __forceinline__ float fast_tanh(float x) {
    float e = __expf(2.0f * x);
    return (e - 1.0f) * __builtin_amdgcn_rcpf(e + 1.0f);
}
typedef unsigned long long u64;
__device__ __forceinline__ u64 shflx64(u64 v, int m) {
    uint32_t lo = (uint32_t)__shfl_xor((int)(uint32_t)v, m, 64);
    uint32_t hi = (uint32_t)__shfl_xor((int)(uint32_t)(v >> 32), m, 64);
    return ((u64)hi << 32) | lo;
}
__device__ __forceinline__ u64 maxu64(u64 a, u64 b) { return a > b ? a : b; }
__device__ __forceinline__ u64 minu64(u64 a, u64 b) { return a < b ? a : b; }

// ------------- prep: transpose weights / fold biases into ws; init out with bias -------------
extern "C" __global__ void dcnn_prep(const float* __restrict__ w1, const float* __restrict__ b1,
                                     const float* __restrict__ w2, const float* __restrict__ b2,
                                     const float* __restrict__ fcb, float* __restrict__ out,
                                     float* __restrict__ ws) {
    int i = blockIdx.x * 256 + threadIdx.x;   // 96*256 == 24576
    if (i < 3072) out[i] = fcb[i % 6];        // out[s*6+n] = fcb[n]
    if (i < W2T_OFF) {                        // w1t[d][k][f] = w1[(d*8+f)*7 + k]
        int d = i / 56, r = i % 56, k = r / 8, f = r % 8;
        ws[i] = w1[(d * 8 + f) * 7 + k];
    } else if (i < B1C_OFF) {                 // w2t[g][ic][k][f2] = w2[((g*16+f2)*8+ic)*5+k]
        int q = i - W2T_OFF;
        int g = q / 640, r = q % 640;
        int ic = r / 80, r2 = r % 80;
        int k = r2 / 16, f2 = r2 % 16;
        ws[i] = w2[((g * 16 + f2) * 8 + ic) * 5 + k];
    } else if (i < B2C_OFF) {                 // b1c[r2][f] = b1[2r2*8+f] + b1[(2r2+1)*8+f]
        int q = i - B1C_OFF;
        int r2 = q / 8, f = q % 8;
        ws[i] = b1[(2 * r2) * 8 + f] + b1[(2 * r2 + 1) * 8 + f];
    } else {                                  // b2c[r3][f2]
        int q = i - B2C_OFF;
        int r3 = q / 16, f2 = q % 16;
        ws[i] = b2[(2 * r3) * 16 + f2] + b2[(2 * r3 + 1) * 16 + f2];
    }
}

// ------------- main: one wave = one (slice, rs-half) task; R12 structure -------------
// Block = 256 thr (4 waves) = 2 slices x 2 rs-halves of ONE sample; grid 4096.
// R13 lesson: smaller blocks (128thr/8192) did NOT raise occupancy and doubled
// FETCH -> reverted. R14: select simplified via the invariant
// count(u>=pre)=g+e>=K => need=K-g<=e; no-refine <=> count(u>=pre)==K, in which
// case keep = (u>=pre) (ALL class ties kept) -- the tie-rank machinery and the
// separate class-count phase are dead in the common path. count(u>=pre) is the
// na of the last ACCEPTED radix step (tracked in-loop). Refine detection
// (ge > K) is provably identical to the old (K-g < e). Bit-identical output.
// R12: rcp-tanh + dense post-pass. R11: v_pk_fma_f32 convs. R9: waves_per_eu(4,8)
// ((6,8) over-squeezed to 40 VGPR + spill). R8: select stays 2-way interleaved.
// R3: all acc/u indices compile-time (runtime index => array to scratch).
extern "C" __global__
__attribute__((amdgpu_flat_work_group_size(256, 256), amdgpu_waves_per_eu(4, 8)))
void dcnn_main(const int* __restrict__ x, const float* __restrict__ emb,
               const float* __restrict__ fcw, const float* __restrict__ ws,
               float* __restrict__ out) {
    __shared__ float uni[4 * WREG];       // 17920 B
    __shared__ int   xs[S_LEN];           // 1 KB
    __shared__ float p2loc[128];          // this block's 128 FC features (raw, pre-tanh)
    __shared__ float fred[2][6];

    const int tid    = threadIdx.x;
    const int lane   = tid & 63;
    const int wv     = __builtin_amdgcn_readfirstlane(tid >> 6);  // 0..3
    const int sample = blockIdx.x >> 3;
    const int q8     = blockIdx.x & 7;
    const int sl     = q8 * 2 + (wv >> 1);   // global slice r3 in [0,16)
    const int rs     = wv & 1;               // which half of the fold pair

    const float* w1t = ws + W1T_OFF;
    const float* w2t = ws + W2T_OFF;
    const float* b1c = ws + B1C_OFF;
    const float* b2c = ws + B2C_OFF;

    xs[tid] = x[sample * S_LEN + tid];
    __syncthreads();

    float*  reg   = uni + wv * WREG;
    float2* rowsW = (float2*)reg;          // 272 float2 = 544 floats
    float*  p1w   = reg;                   // [f:8][140]

    // ---- guards + stage 2 embedding rows (d = 4sl+2rs, +1) as float2 per j ----
    if (lane < 8) {
        rowsW[lane]       = make_float2(0.f, 0.f);
        rowsW[264 + lane] = make_float2(0.f, 0.f);
    }
    const int dbase = 4 * sl + 2 * rs;
#pragma unroll
    for (int m = 0; m < 4; ++m) {
        int j  = lane + 64 * m;            // input pos 0..255
        int xi = xs[j];
        rowsW[8 + j] = *(const float2*)(emb + (size_t)xi * 64 + dbase);
    }

    // ---- conv1 (K=7, depthwise) + fold: 8 channels as 4 packed pairs ----
    v2f acc2[4][5];
#pragma unroll
    for (int j = 0; j < 4; ++j) {
        v2f bz = *(const v2f*)(b1c + (2 * sl + rs) * 8 + 2 * j);
#pragma unroll
        for (int m = 0; m < 5; ++m) acc2[j][m] = bz;
    }
    int tA[5];
#pragma unroll
    for (int m = 0; m < 5; ++m) { int t = lane + 64 * m; tA[m] = (t < OUT1) ? t : (OUT1 - 1); }

#pragma unroll 1
    for (int k = 0; k < 7; ++k) {
        v2f wa[4], wb[4];
#pragma unroll
        for (int j = 0; j < 4; ++j) {
            wa[j] = *(const v2f*)(w1t + (dbase * 7 + k) * 8 + 2 * j);
            wb[j] = *(const v2f*)(w1t + ((dbase + 1) * 7 + k) * 8 + 2 * j);
        }
#pragma unroll
        for (int m = 0; m < 5; ++m) {
            float2 v = rowsW[tA[m] + 2 + k];   // j = t-6+k, +8 guard offset
            v2f vx = { v.x, v.x };
            v2f vy = { v.y, v.y };
#pragma unroll
            for (int j = 0; j < 4; ++j) {
                acc2[j][m] = fma2(wa[j], vx, acc2[j][m]);
                acc2[j][m] = fma2(wb[j], vy, acc2[j][m]);
            }
        }
    }

    // ---- p1 guards (rows region dead; p1 aliases it). 64 lanes = 8 ch x 8 slots ----
    {
        int c = lane >> 3, j = lane & 7;
        int pos = (j < 4) ? j : (131 + j);
        p1w[c * 140 + pos] = 0.f;
    }

    // ---- exact order-preserving top-131 per channel, 2 channels interleaved ----
    // 16-bit radix with tracked accepted-count ge; no-refine (ge==K) path keeps
    // exactly {u >= pre} with plain compaction. Writes RAW values.
#pragma unroll
    for (int cp = 0; cp < 4; ++cp) {
        uint32_t uA[5], uB[5];
#pragma unroll
        for (int m = 0; m < 4; ++m) {          // t = lane+64m < 256 < OUT1 always
            uA[m] = f2ord(acc2[cp][m].x);
            uB[m] = f2ord(acc2[cp][m].y);
        }
        uA[4] = (lane < 6) ? f2ord(acc2[cp][4].x) : 0u;   // t=lane+256 < 262
        uB[4] = (lane < 6) ? f2ord(acc2[cp][4].y) : 0u;
        uint32_t preA = 0, preB = 0;
        int geA = 0x7FFFFFFF, geB = 0x7FFFFFFF;   // count(u>=pre) at last accept
#pragma unroll 1
        for (int bit = 31; bit >= 16; --bit) {
            uint32_t cA = preA | (1u << bit);
            uint32_t cB = preB | (1u << bit);
            int na = 0, nb = 0;
#pragma unroll
            for (int m = 0; m < 5; ++m) {
                na += __popcll(__ballot(uA[m] >= cA));
                nb += __popcll(__ballot(uB[m] >= cB));
            }
            if (na >= K1SEL) { preA = cA; geA = na; }
            if (nb >= K1SEL) { preB = cB; geB = nb; }
        }
        float* dstA = p1w + (2 * cp) * 140 + 4;
        float* dstB = p1w + (2 * cp + 1) * 140 + 4;
        if (geA == K1SEL && geB == K1SEL) {
            // common path: class boundary exact -> keep = (u >= pre), all ties kept
            int kpA = 0, kpB = 0;
#pragma unroll
            for (int m = 0; m < 5; ++m) {
                unsigned long long kmA = __ballot(uA[m] >= preA);
                unsigned long long kmB = __ballot(uB[m] >= preB);
                int posA = kpA + lane_prefix(kmA);     // order-preserving compaction
                int posB = kpB + lane_prefix(kmB);
                if (uA[m] >= preA) dstA[posA] = ord2f(uA[m]);
                if (uB[m] >= preB) dstB[posB] = ord2f(uB[m]);
                kpA += __popcll(kmA); kpB += __popcll(kmB);
            }
        } else {
            // rare path: boundary inside a 16-bit class -> refine low bits fully
#pragma unroll 1
            for (int bit = 15; bit >= 0; --bit) {
                uint32_t cA = preA | (1u << bit);
                uint32_t cB = preB | (1u << bit);
                int na = 0, nb = 0;
#pragma unroll
                for (int m = 0; m < 5; ++m) {
                    na += __popcll(__ballot(uA[m] >= cA));
                    nb += __popcll(__ballot(uB[m] >= cB));
                }
                if (na >= K1SEL) preA = cA;
                if (nb >= K1SEL) preB = cB;
            }
            int cgtA = 0, cgtB = 0;
#pragma unroll
            for (int m = 0; m < 5; ++m) {
                cgtA += __popcll(__ballot(uA[m] > preA));
                cgtB += __popcll(__ballot(uB[m] > preB));
            }
            const int needA = K1SEL - cgtA;            // #ties kept (earliest t first)
            const int needB = K1SEL - cgtB;
            int eqA = 0, kpA = 0, eqB = 0, kpB = 0;
#pragma unroll
            for (int m = 0; m < 5; ++m) {
                unsigned long long emA = __ballot(uA[m] == preA);
                unsigned long long emB = __ballot(uB[m] == preB);
                int erA = eqA + lane_prefix(emA);
                int erB = eqB + lane_prefix(emB);
                bool keepA = (uA[m] > preA) || ((uA[m] == preA) && (erA < needA));
                bool keepB = (uB[m] > preB) || ((uB[m] == preB) && (erB < needB));
                unsigned long long kmA = __ballot(keepA);
                unsigned long long kmB = __ballot(keepB);
                int posA = kpA + lane_prefix(kmA);
                int posB = kpB + lane_prefix(kmB);
                if (keepA) dstA[posA] = ord2f(uA[m]);
                if (keepB) dstB[posB] = ord2f(uB[m]);
                eqA += __popcll(emA); kpA += __popcll(kmA);
                eqB += __popcll(emB); kpB += __popcll(kmB);
            }
        }
    }

    // ---- dense tanh post-pass over the whole p1 region (1120 floats) ----
    // guards are 0 and tanh(0)=0; slot 139 of each channel is never read.
#pragma unroll
    for (int i = 0; i < 17; ++i) {
        int idx = lane + 64 * i;
        p1w[idx] = fast_tanh(p1w[idx]);
    }
    if (lane < 32) {
        int idx = lane + 64 * 17;
        p1w[idx] = fast_tanh(p1w[idx]);
    }

    // ---- conv2 partial: group g = 2sl+rs; 16 f2 as 8 packed pairs ----
    v2f a2v[8][3];
    {
        const v2f* b2v = (const v2f*)(b2c + sl * 16);
#pragma unroll
        for (int j = 0; j < 8; ++j) {
            v2f bz = rs ? (v2f){0.f, 0.f} : b2v[j];   // pre-folded bias counted once
            a2v[j][0] = bz; a2v[j][1] = bz; a2v[j][2] = bz;
        }
    }
    int tB[3];
#pragma unroll
    for (int tm = 0; tm < 3; ++tm) { int t = lane + 64 * tm; tB[tm] = (t < OUT2) ? t : (OUT2 - 1); }

    const int g = 2 * sl + rs;
#pragma unroll 1
    for (int ic = 0; ic < 8; ++ic) {
        const float* src = p1w + ic * 140;   // logical t' = idx - 4
        float win[3][5];                     // straight-line window loads (ds_read2-able)
#pragma unroll
        for (int m = 0; m < 3; ++m) {
            win[m][0] = src[tB[m]];     win[m][1] = src[tB[m] + 1];
            win[m][2] = src[tB[m] + 2]; win[m][3] = src[tB[m] + 3];
            win[m][4] = src[tB[m] + 4];
        }
#pragma unroll
        for (int k = 0; k < 5; ++k) {
            const v2f* wv2 = (const v2f*)(w2t + ((g * 8 + ic) * 5 + k) * 16);
            v2f s0 = { win[0][k], win[0][k] };
            v2f s1 = { win[1][k], win[1][k] };
            v2f s2 = { win[2][k], win[2][k] };
#pragma unroll
            for (int j = 0; j < 8; ++j) {
                v2f w = wv2[j];
                a2v[j][0] = fma2(w, s0, a2v[j][0]);
                a2v[j][1] = fma2(w, s1, a2v[j][1]);
                a2v[j][2] = fma2(w, s2, a2v[j][2]);
            }
        }
    }

    // ---- cross-wave fold (a2 sum) in the pair's dead p1 regions ----
    float* scr = uni + (wv & ~1) * WREG;     // 2240 floats >= 16*137
    __syncthreads();                          // both halves' conv2 done
    if (rs) {
#pragma unroll
        for (int j = 0; j < 8; ++j) {
            scr[(2 * j) * 137 + lane]           = a2v[j][0].x;
            scr[(2 * j + 1) * 137 + lane]       = a2v[j][0].y;
            scr[(2 * j) * 137 + lane + 64]      = a2v[j][1].x;
            scr[(2 * j + 1) * 137 + lane + 64]  = a2v[j][1].y;
            if (lane + 128 < OUT2) {
                scr[(2 * j) * 137 + lane + 128]     = a2v[j][2].x;
                scr[(2 * j + 1) * 137 + lane + 128] = a2v[j][2].y;
            }
        }
    }
    __syncthreads();
    if (!rs) {
#pragma unroll
        for (int j = 0; j < 8; ++j) {
            scr[(2 * j) * 137 + lane]           += a2v[j][0].x;
            scr[(2 * j + 1) * 137 + lane]       += a2v[j][0].y;
            scr[(2 * j) * 137 + lane + 64]      += a2v[j][1].x;
            scr[(2 * j + 1) * 137 + lane + 64]  += a2v[j][1].y;
            if (lane + 128 < OUT2) {
                scr[(2 * j) * 137 + lane + 128]     += a2v[j][2].x;
                scr[(2 * j + 1) * 137 + lane + 128] += a2v[j][2].y;
            }
        }
    }
    __syncthreads();                          // sums visible to both waves

    // ---- top-4 (value desc, tie -> lower t): BOTH waves, 8 lanes per f2 ----
    // 64-bit key = (f2ord(v)<<32) | (0xFFFFFFFF - t); desc == value desc, tie t asc.
    {
        const int f2o = (lane >> 3) + 8 * rs;  // this wave's 8 f2 channels
        const int seg = lane & 7;              // segment of 17 (last has 16)
        const int tstart = seg * 17;
        const int tend = (seg == 7) ? (OUT2 - 119) : 17;
        const float* src = scr + f2o * 137 + tstart;
        const uint32_t tb = 0xFFFFFFFFu - (uint32_t)tstart;
        u64 L0 = 0, L1 = 0, L2 = 0, L3 = 0;    // sentinels (lose to any finite)
#pragma unroll 1
        for (int i = 0; i < 17; ++i) {
            float v = src[(i < tend) ? i : 0];
            u64 kk = ((u64)f2ord(v) << 32) | (u64)(tb - (uint32_t)i);
            if (i >= tend) kk = 0;
            bool b0 = kk > L0, b1 = kk > L1, b2 = kk > L2, b3 = kk > L3;
            L3 = b3 ? (b2 ? L2 : kk) : L3;
            L2 = b2 ? (b1 ? L1 : kk) : L2;
            L1 = b1 ? (b0 ? L0 : kk) : L1;
            L0 = b0 ? kk : L0;
        }
        // merge 8 segments: 3 shfl rounds; r_i = min_{j+l=i} max(A_j,B_l)
#pragma unroll
        for (int d = 1; d <= 4; d <<= 1) {
            u64 M0 = shflx64(L0, d), M1 = shflx64(L1, d);
            u64 M2 = shflx64(L2, d), M3 = shflx64(L3, d);
            u64 r0 = maxu64(L0, M0);
            u64 r1 = minu64(maxu64(L0, M1), maxu64(L1, M0));
            u64 r2 = minu64(minu64(maxu64(L0, M2), maxu64(L1, M1)), maxu64(L2, M0));
            u64 r3k = minu64(minu64(maxu64(L0, M3), maxu64(L1, M2)),
                             minu64(maxu64(L2, M1), maxu64(L3, M0)));
            L0 = r0; L1 = r1; L2 = r2; L3 = r3k;
        }
        if (seg == 0) {
            // reorder by t ascending == low-32 word descending; emit raw (tanh in FC)
#define CSW2(a, bb) { if ((uint32_t)(bb) > (uint32_t)(a)) { u64 tt = (a); (a) = (bb); (bb) = tt; } }
            CSW2(L0, L1); CSW2(L2, L3); CSW2(L0, L2); CSW2(L1, L3); CSW2(L1, L2);
#undef CSW2
            float* qp = &p2loc[(wv >> 1) * 64 + f2o * 4];
            qp[0] = ord2f((uint32_t)(L0 >> 32));
            qp[1] = ord2f((uint32_t)(L1 >> 32));
            qp[2] = ord2f((uint32_t)(L2 >> 32));
            qp[3] = ord2f((uint32_t)(L3 >> 32));
        }
    }
    __syncthreads();

    // ---- FC partial over this block's 128 features (waves 0-1) + atomic out ----
    if (wv < 2) {
        float pv = fast_tanh(p2loc[tid]);
        float part[6];
#pragma unroll
        for (int n = 0; n < 6; ++n) part[n] = pv * fcw[n * 1024 + q8 * 128 + tid];
#pragma unroll
        for (int n = 0; n < 6; ++n) {
            float s = part[n];
#pragma unroll
            for (int off = 32; off > 0; off >>= 1) s += __shfl_xor(s, off, 64);
            if (lane == 0) fred[wv][n] = s;
        }
    }
    __syncthreads();
    if (tid < 6)
        atomicAdd(&out[sample * 6 + tid], fred[0][tid] + fred[1][tid]);
}

extern "C" void kernel_launch(void* const* d_in, const int* in_sizes, int n_in,
                              void* d_out, int out_size, void* d_ws, size_t ws_size,
                              hipStream_t stream) {
    (void)in_sizes; (void)n_in; (void)out_size; (void)ws_size;
    const int*   x   = (const int*)d_in[0];
    const float* emb = (const float*)d_in[1];
    const float* w1  = (const float*)d_in[2];
    const float* b1  = (const float*)d_in[3];
    const float* w2  = (const float*)d_in[4];
    const float* b2  = (const float*)d_in[5];
    const float* fcw = (const float*)d_in[6];
    const float* fcb = (const float*)d_in[7];
    float* outp = (float*)d_out;
    float* wsf  = (float*)d_ws;   // weights+biases: 24576 floats

    dcnn_prep<<<96, 256, 0, stream>>>(w1, b1, w2, b2, fcb, outp, wsf);
    dcnn_main<<<4096, 256, 0, stream>>>(x, emb, fcw, wsf, outp);
}